// Round 9
// baseline (102.856 us; speedup 1.0000x reference)
//
#include <hip/hip_runtime.h>
#include <float.h>

#define N_BINS 20
#define C 128
#define NVAL (2 * N_BINS)      // 20 conf-sums + 20 acc-sums
#define S_SLOTS 64             // spread-slots for the cross-block flush
#define SLOT_FLOATS (S_SLOTS * NVAL)   // 2560 floats = 10.24 KB

typedef float f32x4 __attribute__((ext_vector_type(4)));

// ---------------------------------------------------------------------------
// Kernel 1: per-row max/argmax + per-block partial histogram.
// Streaming core is byte-identical to R6/R8 (proven 5.35 TB/s).
//
// Layout: 8 lanes per row, each lane loads 4x float4; per load instruction
// the wave covers 8 rows x one full 128-B line. 3-step butterfly within
// 8-lane groups, lowest-index tiebreak (first-occurrence argmax).
//
// Flush (changed vs R8): 40 atomicAdds into slot (blockIdx & 63), layout
// [slot][value] -> each block's 40 adds are CONTIGUOUS (2 cache lines).
// ~31 blocks share a slot, completions are staggered -> contention hidden.
// Slots are zeroed by a 10-KB hipMemsetAsync before launch (R7-proven
// graph-capturable). The fused-tail design from R7 is deliberately avoided:
// it cratered the hot loop's VGPR allocation.
// ---------------------------------------------------------------------------
__global__ __launch_bounds__(256) void ece_main(const float* __restrict__ outs,
                                                const int* __restrict__ labels,
                                                float* __restrict__ slots,
                                                int n_rows, int n_waves) {
    __shared__ float s_hist[NVAL];

    const int tid = threadIdx.x;
    if (tid < NVAL) s_hist[tid] = 0.0f;
    __syncthreads();

    const int lane = tid & 63;
    const int sub  = lane & 7;    // chunk-column within the row
    const int rsub = lane >> 3;   // which of the wave's 8 rows
    const int gwave = blockIdx.x * 4 + (tid >> 6);

    const f32x4* __restrict__ outs4 = reinterpret_cast<const f32x4*>(outs);

    for (int rowBase = gwave * 8; rowBase < n_rows; rowBase += n_waves * 8) {
        const int row = rowBase + rsub;
        const bool live = (row < n_rows);

        int   lab = -1;
        float bestVal = -FLT_MAX;
        int   bestIdx = 0x7fffffff;

        if (live) {
            if (sub == 0) lab = labels[row];
            const f32x4* p = outs4 + (size_t)row * (C / 4) + sub;
            f32x4 v[4];
            #pragma unroll
            for (int j = 0; j < 4; ++j) v[j] = p[j * 8];

            // strict '>' serial scan in increasing element order
            // (element index of v[j].c = 4*sub + 32*j + c)
            const int b0 = 4 * sub;
            bestVal = v[0].x; bestIdx = b0;
            #pragma unroll
            for (int j = 0; j < 4; ++j) {
                const int b = b0 + 32 * j;
                if (j > 0 && v[j].x > bestVal) { bestVal = v[j].x; bestIdx = b; }
                if (v[j].y > bestVal) { bestVal = v[j].y; bestIdx = b + 1; }
                if (v[j].z > bestVal) { bestVal = v[j].z; bestIdx = b + 2; }
                if (v[j].w > bestVal) { bestVal = v[j].w; bestIdx = b + 3; }
            }
        }

        // 3-step butterfly within each 8-lane group (all 8 lanes share a row)
        #pragma unroll
        for (int m = 1; m <= 4; m <<= 1) {
            const float ov = __shfl_xor(bestVal, m);
            const int   oi = __shfl_xor(bestIdx, m);
            if (ov > bestVal || (ov == bestVal && oi < bestIdx)) {
                bestVal = ov;
                bestIdx = oi;
            }
        }

        if (sub == 0 && live) {
            // bin = clip(ceil(conf*20) - 1, 0, 19): same f32 arithmetic as ref
            int bin = (int)ceilf(bestVal * (float)N_BINS) - 1;
            bin = min(max(bin, 0), N_BINS - 1);
            atomicAdd(&s_hist[bin], bestVal);
            atomicAdd(&s_hist[N_BINS + bin], (bestIdx == lab) ? 1.0f : 0.0f);
        }
    }

    __syncthreads();
    if (tid < NVAL) {
        atomicAdd(&slots[(size_t)(blockIdx.x & (S_SLOTS - 1)) * NVAL + tid],
                  s_hist[tid]);
    }
}

// ---------------------------------------------------------------------------
// Kernel 2: reduce the 64 slots, then ece = sum_b |conf_b - acc_b| / N.
// One block, 256 threads. 10 KB total: coalesced load into LDS (10 rounds),
// per-value sum over 64 slots (stride-40 LDS reads, <=2-way bank alias),
// then one wave computes the final sum.
// ---------------------------------------------------------------------------
__global__ __launch_bounds__(256) void ece_final(const float* __restrict__ slots,
                                                 float* __restrict__ out,
                                                 float inv_n) {
    __shared__ float s_red[SLOT_FLOATS];
    __shared__ float s_tot[NVAL];

    const int tid = threadIdx.x;

    for (int f = tid; f < SLOT_FLOATS; f += 256) s_red[f] = slots[f];
    __syncthreads();

    if (tid < NVAL) {
        float t = 0.0f;
        #pragma unroll
        for (int s = 0; s < S_SLOTS; ++s) t += s_red[s * NVAL + tid];
        s_tot[tid] = t;
    }
    __syncthreads();

    if (tid < 64) {
        float d = (tid < N_BINS) ? fabsf(s_tot[tid] - s_tot[tid + N_BINS])
                                 : 0.0f;
        #pragma unroll
        for (int m = 1; m <= 32; m <<= 1) d += __shfl_xor(d, m);
        if (tid == 0) out[0] = d * inv_n;
    }
}

extern "C" void kernel_launch(void* const* d_in, const int* in_sizes, int n_in,
                              void* d_out, int out_size, void* d_ws, size_t ws_size,
                              hipStream_t stream) {
    const float* outs   = (const float*)d_in[0];
    const int*   labels = (const int*)d_in[1];
    float*       out    = (float*)d_out;
    float*       slots  = (float*)d_ws;

    const int n_rows = in_sizes[1];    // labels count == N
    // 1956 blocks x 4 waves x 8 rows = 62592 rows/sweep; 1e6/62592 = 15.98
    // -> last grid-stride sweep 97.6% full.
    const int blocks  = 1956;
    const int n_waves = blocks * 4;

    // Zero the 64x40 slot array (10.24 KB). Graph-capturable async memset.
    hipMemsetAsync(d_ws, 0, SLOT_FLOATS * sizeof(float), stream);

    hipLaunchKernelGGL(ece_main, dim3(blocks), dim3(256), 0, stream,
                       outs, labels, slots, n_rows, n_waves);
    hipLaunchKernelGGL(ece_final, dim3(1), dim3(256), 0, stream,
                       slots, out, 1.0f / (float)n_rows);
}

// Round 10
// 99.884 us; speedup vs baseline: 1.0297x; 1.0297x over previous
//
#include <hip/hip_runtime.h>
#include <float.h>

#define N_BINS 20
#define C 128
#define NVAL (2 * N_BINS)   // 20 conf-sums + 20 acc-sums

typedef float f32x4 __attribute__((ext_vector_type(4)));

// ---------------------------------------------------------------------------
// Kernel 0 (fallback mode only): zero the shared slot array.
// ---------------------------------------------------------------------------
__global__ void ece_init(float* __restrict__ slots, int total) {
    int t = blockIdx.x * blockDim.x + threadIdx.x;
    if (t < total) slots[t] = 0.0f;
}

// ---------------------------------------------------------------------------
// Kernel 1: per-row max/argmax + per-block partial histogram.
// (R8-proven structure -- best measured: 100.2 us total, stream ~5.35 TB/s.)
//
// Layout: 8 lanes per row, each lane loads 4x float4; per load instruction
// the wave covers 8 rows x one full 128-B line. 3-step butterfly within
// 8-lane groups, lowest-index tiebreak (first-occurrence argmax).
//
// Flush: each block writes its 40-float partial histogram to a PRIVATE slot
// in d_ws (plain stores, fully overwritten every call -> no init kernel, no
// atomic serialization). Slot layout [value j][slot s] -> coalesced final.
// (R7's fused tail and R9's shared-atomic-slot flush both measured SLOWER.)
// ---------------------------------------------------------------------------
__global__ __launch_bounds__(256) void ece_main(const float* __restrict__ outs,
                                                const int* __restrict__ labels,
                                                float* __restrict__ slots,
                                                int n_rows, int n_waves,
                                                int S, int priv) {
    __shared__ float s_hist[NVAL];

    const int tid = threadIdx.x;
    if (tid < NVAL) s_hist[tid] = 0.0f;
    __syncthreads();

    const int lane = tid & 63;
    const int sub  = lane & 7;    // chunk-column within the row
    const int rsub = lane >> 3;   // which of the wave's 8 rows
    const int gwave = blockIdx.x * 4 + (tid >> 6);

    const f32x4* __restrict__ outs4 = reinterpret_cast<const f32x4*>(outs);

    for (int rowBase = gwave * 8; rowBase < n_rows; rowBase += n_waves * 8) {
        const int row = rowBase + rsub;
        const bool live = (row < n_rows);

        int   lab = -1;
        float bestVal = -FLT_MAX;
        int   bestIdx = 0x7fffffff;

        if (live) {
            if (sub == 0) lab = labels[row];
            const f32x4* p = outs4 + (size_t)row * (C / 4) + sub;
            f32x4 v[4];
            #pragma unroll
            for (int j = 0; j < 4; ++j) v[j] = p[j * 8];

            // strict '>' serial scan in increasing element order
            // (element index of v[j].c = 4*sub + 32*j + c)
            const int b0 = 4 * sub;
            bestVal = v[0].x; bestIdx = b0;
            #pragma unroll
            for (int j = 0; j < 4; ++j) {
                const int b = b0 + 32 * j;
                if (j > 0 && v[j].x > bestVal) { bestVal = v[j].x; bestIdx = b; }
                if (v[j].y > bestVal) { bestVal = v[j].y; bestIdx = b + 1; }
                if (v[j].z > bestVal) { bestVal = v[j].z; bestIdx = b + 2; }
                if (v[j].w > bestVal) { bestVal = v[j].w; bestIdx = b + 3; }
            }
        }

        // 3-step butterfly within each 8-lane group (all 8 lanes share a row)
        #pragma unroll
        for (int m = 1; m <= 4; m <<= 1) {
            const float ov = __shfl_xor(bestVal, m);
            const int   oi = __shfl_xor(bestIdx, m);
            if (ov > bestVal || (ov == bestVal && oi < bestIdx)) {
                bestVal = ov;
                bestIdx = oi;
            }
        }

        if (sub == 0 && live) {
            // bin = clip(ceil(conf*20) - 1, 0, 19): same f32 arithmetic as ref
            int bin = (int)ceilf(bestVal * (float)N_BINS) - 1;
            bin = min(max(bin, 0), N_BINS - 1);
            atomicAdd(&s_hist[bin], bestVal);
            atomicAdd(&s_hist[N_BINS + bin], (bestIdx == lab) ? 1.0f : 0.0f);
        }
    }

    __syncthreads();
    if (tid < NVAL) {
        const int slot = priv ? blockIdx.x : (blockIdx.x & (S - 1));
        if (priv) slots[(size_t)tid * S + slot] = s_hist[tid];
        else      atomicAdd(&slots[(size_t)tid * S + slot], s_hist[tid]);
    }
}

// ---------------------------------------------------------------------------
// Kernel 2: reduce S slots per value, then ece = sum_b |conf_b - acc_b| / N.
// One block, 1024 threads: 16 chunk-threads per value (64 groups, 40 active).
// S is a multiple of 4 -> each value-row is S/4 aligned float4s; x4 loads
// with 4-accumulator unroll. Coalesced: 16 consecutive threads read 16
// consecutive float4s.
// ---------------------------------------------------------------------------
__global__ __launch_bounds__(1024) void ece_final(const float* __restrict__ slots,
                                                  float* __restrict__ out,
                                                  int S, float inv_n) {
    __shared__ float red[NVAL][16];
    __shared__ float tot[NVAL];

    const int tid = threadIdx.x;
    const int j = tid >> 4;      // value index 0..63 (40 active)
    const int c = tid & 15;      // chunk within value

    if (j < NVAL) {
        const f32x4* base4 =
            reinterpret_cast<const f32x4*>(slots + (size_t)j * S);
        const int nv4 = S >> 2;
        f32x4 a0 = {0.f, 0.f, 0.f, 0.f}, a1 = a0, a2 = a0, a3 = a0;
        int s = c;
        for (; s + 48 < nv4; s += 64) {
            a0 += base4[s];
            a1 += base4[s + 16];
            a2 += base4[s + 32];
            a3 += base4[s + 48];
        }
        for (; s < nv4; s += 16) a0 += base4[s];
        const f32x4 aa = (a0 + a1) + (a2 + a3);
        red[j][c] = (aa.x + aa.y) + (aa.z + aa.w);
    }
    __syncthreads();

    if (tid < NVAL) {
        float t2 = 0.f;
        #pragma unroll
        for (int k = 0; k < 16; ++k) t2 += red[tid][k];
        tot[tid] = t2;
    }
    __syncthreads();

    if (tid < 64) {
        float d = (tid < N_BINS) ? fabsf(tot[tid] - tot[tid + N_BINS]) : 0.0f;
        #pragma unroll
        for (int m = 1; m <= 32; m <<= 1) d += __shfl_xor(d, m);
        if (tid == 0) out[0] = d * inv_n;
    }
}

extern "C" void kernel_launch(void* const* d_in, const int* in_sizes, int n_in,
                              void* d_out, int out_size, void* d_ws, size_t ws_size,
                              hipStream_t stream) {
    const float* outs   = (const float*)d_in[0];
    const int*   labels = (const int*)d_in[1];
    float*       out    = (float*)d_out;
    float*       slots  = (float*)d_ws;

    const int n_rows = in_sizes[1];    // labels count == N
    // 1956 blocks x 4 waves x 8 rows = 62592 rows/sweep; 1e6/62592 = 15.98
    // -> last grid-stride sweep 97.9% full; 1956 % 4 == 0 for x4 final reads.
    const int blocks  = 1956;
    const int n_waves = blocks * 4;

    int S, priv;
    if (ws_size >= (size_t)blocks * NVAL * sizeof(float)) {
        S = blocks; priv = 1;          // block-private slots, plain stores
    } else {
        priv = 0;                      // shared slots + atomics (+ init)
        S = 4;                         // power of two (>=4, multiple of 4)
        while ((size_t)(S * 2) * NVAL * sizeof(float) <= ws_size && S * 2 < blocks)
            S <<= 1;
    }

    if (!priv) {
        const int total = S * NVAL;
        hipLaunchKernelGGL(ece_init, dim3((total + 255) / 256), dim3(256), 0,
                           stream, slots, total);
    }
    hipLaunchKernelGGL(ece_main, dim3(blocks), dim3(256), 0, stream,
                       outs, labels, slots, n_rows, n_waves, S, priv);
    hipLaunchKernelGGL(ece_final, dim3(1), dim3(1024), 0, stream,
                       slots, out, S, 1.0f / (float)n_rows);
}